// Round 3
// baseline (632.413 us; speedup 1.0000x reference)
//
#include <hip/hip_runtime.h>
#include <hip/hip_bf16.h>

#define T_ 2048
#define H_ 16
#define DQK_ 192
#define SCALE_ 0.07216878364870322f  // 192^-0.5

typedef __bf16 bf16x8 __attribute__((ext_vector_type(8)));
typedef float f32x4 __attribute__((ext_vector_type(4)));

// load 8 consecutive elements as bf16x8, converting if needed
__device__ inline bf16x8 load8(const __bf16* p) {
    return *reinterpret_cast<const bf16x8*>(p);
}
__device__ inline bf16x8 load8(const float* p) {
    const float4* f = reinterpret_cast<const float4*>(p);
    float4 a = f[0], b = f[1];
    bf16x8 r;
    r[0] = (__bf16)a.x; r[1] = (__bf16)a.y; r[2] = (__bf16)a.z; r[3] = (__bf16)a.w;
    r[4] = (__bf16)b.x; r[5] = (__bf16)b.y; r[6] = (__bf16)b.z; r[7] = (__bf16)b.w;
    return r;
}

// ---------------- Generic GEMM: C[M,N] = A[M,K] @ B[K,N] --------------------
// 64x64 tile, BK=32, 4 waves (2x2 of 32x32 each = 2x2 MFMA 16x16 frags).
template <typename TA, typename TB, typename TC>
__global__ __launch_bounds__(256) void gemm_any(
    const TA* __restrict__ A, const TB* __restrict__ B,
    TC* __restrict__ C, int M, int N, int K)
{
    __shared__ __bf16 As[64][40];   // [m][k], +8 pad keeps rows 16B-aligned
    __shared__ __bf16 Bt[64][40];   // transposed: [n][k]

    const int tid  = threadIdx.x;
    const int lane = tid & 63;
    const int l15  = lane & 15;
    const int lg   = lane >> 4;
    const int wid  = tid >> 6;
    const int wr   = (wid >> 1) * 32;
    const int wc   = (wid & 1) * 32;
    const int m0   = blockIdx.x * 64;
    const int n0   = blockIdx.y * 64;

    const int ar   = tid >> 2;        // 0..63
    const int ac   = (tid & 3) * 8;   // 0..24
    const int brow = tid >> 3;        // 0..31 (k)
    const int bcol = (tid & 7) * 8;   // 0..56 (n)

    f32x4 acc[2][2] = {};

    for (int k0 = 0; k0 < K; k0 += 32) {
        bf16x8 av = load8(A + (size_t)(m0 + ar) * K + k0 + ac);
        bf16x8 bv = load8(B + (size_t)(k0 + brow) * N + n0 + bcol);
        __syncthreads();   // previous iteration's reads done
        *reinterpret_cast<bf16x8*>(&As[ar][ac]) = av;
        #pragma unroll
        for (int e = 0; e < 8; ++e) Bt[bcol + e][brow] = bv[e];
        __syncthreads();   // staging visible

        bf16x8 af0 = *reinterpret_cast<const bf16x8*>(&As[wr + l15][lg * 8]);
        bf16x8 af1 = *reinterpret_cast<const bf16x8*>(&As[wr + 16 + l15][lg * 8]);
        bf16x8 bf0 = *reinterpret_cast<const bf16x8*>(&Bt[wc + l15][lg * 8]);
        bf16x8 bf1 = *reinterpret_cast<const bf16x8*>(&Bt[wc + 16 + l15][lg * 8]);

        acc[0][0] = __builtin_amdgcn_mfma_f32_16x16x32_bf16(af0, bf0, acc[0][0], 0, 0, 0);
        acc[0][1] = __builtin_amdgcn_mfma_f32_16x16x32_bf16(af0, bf1, acc[0][1], 0, 0, 0);
        acc[1][0] = __builtin_amdgcn_mfma_f32_16x16x32_bf16(af1, bf0, acc[1][0], 0, 0, 0);
        acc[1][1] = __builtin_amdgcn_mfma_f32_16x16x32_bf16(af1, bf1, acc[1][1], 0, 0, 0);
    }

    #pragma unroll
    for (int mi = 0; mi < 2; ++mi)
        #pragma unroll
        for (int ni = 0; ni < 2; ++ni)
            #pragma unroll
            for (int e = 0; e < 4; ++e) {
                int r = m0 + wr + mi * 16 + lg * 4 + e;   // C/D: row=(lane>>4)*4+reg
                int c = n0 + wc + ni * 16 + l15;          //      col=lane&15
                C[(size_t)r * N + c] = (TC)acc[mi][ni][e];
            }
}

// ---------------- RMSNorm over rows (bf16 in/out, f32 gamma) ----------------
__global__ __launch_bounds__(256) void rmsnorm_k(
    const __bf16* __restrict__ in, int in_stride,
    const float* __restrict__ w,
    __bf16* __restrict__ out, int out_stride, int W)
{
    const int t = blockIdx.x, tid = threadIdx.x;
    const __bf16* row = in + (size_t)t * in_stride;
    float x[8];
    float ss = 0.f;
    const bool act = tid * 8 < W;
    if (act) {
        bf16x8 v = *reinterpret_cast<const bf16x8*>(row + tid * 8);
        #pragma unroll
        for (int e = 0; e < 8; ++e) { x[e] = (float)v[e]; ss += x[e] * x[e]; }
    }
    #pragma unroll
    for (int m = 1; m < 64; m <<= 1) ss += __shfl_xor(ss, m, 64);
    __shared__ float red[4];
    if ((tid & 63) == 0) red[tid >> 6] = ss;
    __syncthreads();
    float tot = red[0] + red[1] + red[2] + red[3];
    float scale = rsqrtf(tot / (float)W + 1e-6f);
    if (act) {
        float4 w0 = *reinterpret_cast<const float4*>(w + tid * 8);
        float4 w1 = *reinterpret_cast<const float4*>(w + tid * 8 + 4);
        bf16x8 o;
        o[0] = (__bf16)(x[0] * scale * w0.x); o[1] = (__bf16)(x[1] * scale * w0.y);
        o[2] = (__bf16)(x[2] * scale * w0.z); o[3] = (__bf16)(x[3] * scale * w0.w);
        o[4] = (__bf16)(x[4] * scale * w1.x); o[5] = (__bf16)(x[5] * scale * w1.y);
        o[6] = (__bf16)(x[6] * scale * w1.z); o[7] = (__bf16)(x[7] * scale * w1.w);
        *reinterpret_cast<bf16x8*>(out + (size_t)t * out_stride + tid * 8) = o;
    }
}

// ---------------- RoPE + head assembly ---------------------------------------
__global__ __launch_bounds__(256) void assemble_rope(
    const int* __restrict__ positions,
    const __bf16* __restrict__ q,
    const __bf16* __restrict__ kv,
    const __bf16* __restrict__ latent,
    __bf16* __restrict__ qh, __bf16* __restrict__ kh, __bf16* __restrict__ vh)
{
    const int t = blockIdx.x, tid = threadIdx.x;
    __shared__ float cs[32], sn[32], kpe[64];
    if (tid < 32) {
        float pos = (float)positions[t];
        float invf = powf(10000.f, -(float)tid / 32.f);
        float ang = pos * invf;
        float c = cosf(ang), s = sinf(ang);
        cs[tid] = c; sn[tid] = s;
        float x1 = (float)latent[(size_t)t * 576 + 512 + 2 * tid];
        float x2 = (float)latent[(size_t)t * 576 + 513 + 2 * tid];
        kpe[2 * tid]     = x1 * c - x2 * s;
        kpe[2 * tid + 1] = x2 * c + x1 * s;
    }
    __syncthreads();
    const __bf16* qrow  = q  + (size_t)t * 3072;
    const __bf16* kvrow = kv + (size_t)t * 4096;
    // nope parts + v
    for (int idx = tid; idx < 2048; idx += 256) {
        int h = idx >> 7, d = idx & 127;
        qh[((size_t)h * T_ + t) * DQK_ + d] = qrow[h * DQK_ + d];
        kh[((size_t)h * T_ + t) * DQK_ + d] = kvrow[h * 256 + d];
        vh[((size_t)h * T_ + t) * 128 + d]  = kvrow[h * 256 + 128 + d];
    }
    // q rope pairs
    for (int idx = tid; idx < 512; idx += 256) {
        int h = idx >> 5, i = idx & 31;
        float x1 = (float)qrow[h * DQK_ + 128 + 2 * i];
        float x2 = (float)qrow[h * DQK_ + 129 + 2 * i];
        qh[((size_t)h * T_ + t) * DQK_ + 128 + 2 * i] = (__bf16)(x1 * cs[i] - x2 * sn[i]);
        qh[((size_t)h * T_ + t) * DQK_ + 129 + 2 * i] = (__bf16)(x2 * cs[i] + x1 * sn[i]);
    }
    // k_pe broadcast to all heads
    for (int idx = tid; idx < 1024; idx += 256) {
        int h = idx >> 6, j = idx & 63;
        kh[((size_t)h * T_ + t) * DQK_ + 128 + j] = (__bf16)kpe[j];
    }
}

// ---------------- Flash attention (causal), 1 wave = 16 q rows ---------------
__global__ __launch_bounds__(256) void attn_flash(
    const __bf16* __restrict__ qh, const __bf16* __restrict__ kh,
    const __bf16* __restrict__ vh, __bf16* __restrict__ attn)
{
    const int tid = threadIdx.x, lane = tid & 63, wid = tid >> 6;
    const int l15 = lane & 15, lg = lane >> 4;
    const int h  = blockIdx.y;
    const int q0 = blockIdx.x * 64 + wid * 16;

    __shared__ __bf16 plds[4][16][32];

    const __bf16* Q  = qh + (size_t)h * T_ * DQK_;
    const __bf16* Kp = kh + (size_t)h * T_ * DQK_;
    const __bf16* Vp = vh + (size_t)h * T_ * 128;

    bf16x8 aq[6];
    #pragma unroll
    for (int c = 0; c < 6; ++c)
        aq[c] = *reinterpret_cast<const bf16x8*>(Q + (size_t)(q0 + l15) * DQK_ + c * 32 + lg * 8);

    f32x4 o[8] = {};
    float m_i[4], l_i[4];
    #pragma unroll
    for (int i = 0; i < 4; ++i) { m_i[i] = -1e30f; l_i[i] = 0.f; }

    const int smax = q0 + 16;   // exclusive bound of needed kv
    for (int s0 = 0; s0 < smax; s0 += 32) {
        f32x4 sa0 = {}, sa1 = {};
        #pragma unroll
        for (int c = 0; c < 6; ++c) {
            bf16x8 k0f = *reinterpret_cast<const bf16x8*>(Kp + (size_t)(s0 + l15) * DQK_ + c * 32 + lg * 8);
            bf16x8 k1f = *reinterpret_cast<const bf16x8*>(Kp + (size_t)(s0 + 16 + l15) * DQK_ + c * 32 + lg * 8);
            sa0 = __builtin_amdgcn_mfma_f32_16x16x32_bf16(aq[c], k0f, sa0, 0, 0, 0);
            sa1 = __builtin_amdgcn_mfma_f32_16x16x32_bf16(aq[c], k1f, sa1, 0, 0, 0);
        }
        const int col0 = s0 + l15, col1 = s0 + 16 + l15;
        #pragma unroll
        for (int i = 0; i < 4; ++i) {
            const int row = q0 + lg * 4 + i;
            float v0 = sa0[i] * SCALE_; if (col0 > row) v0 = -1e30f;
            float v1 = sa1[i] * SCALE_; if (col1 > row) v1 = -1e30f;
            float mx = fmaxf(v0, v1);
            #pragma unroll
            for (int msk = 1; msk < 16; msk <<= 1) mx = fmaxf(mx, __shfl_xor(mx, msk, 64));
            float mnew = fmaxf(m_i[i], mx);
            float f  = __expf(m_i[i] - mnew);
            float p0 = __expf(v0 - mnew);
            float p1 = __expf(v1 - mnew);
            float ps = p0 + p1;
            #pragma unroll
            for (int msk = 1; msk < 16; msk <<= 1) ps += __shfl_xor(ps, msk, 64);
            l_i[i] = l_i[i] * f + ps;
            m_i[i] = mnew;
            #pragma unroll
            for (int n = 0; n < 8; ++n) o[n][i] *= f;
            plds[wid][lg * 4 + i][l15]      = (__bf16)p0;
            plds[wid][lg * 4 + i][16 + l15] = (__bf16)p1;
        }
        asm volatile("s_waitcnt lgkmcnt(0)" ::: "memory");
        bf16x8 pa = *reinterpret_cast<const bf16x8*>(&plds[wid][l15][lg * 8]);
        #pragma unroll
        for (int n = 0; n < 8; ++n) {
            bf16x8 bv;
            #pragma unroll
            for (int e = 0; e < 8; ++e)
                bv[e] = Vp[(size_t)(s0 + lg * 8 + e) * 128 + n * 16 + l15];
            o[n] = __builtin_amdgcn_mfma_f32_16x16x32_bf16(pa, bv, o[n], 0, 0, 0);
        }
    }

    #pragma unroll
    for (int i = 0; i < 4; ++i) {
        float inv = 1.f / l_i[i];
        int row = q0 + lg * 4 + i;
        #pragma unroll
        for (int n = 0; n < 8; ++n)
            attn[(size_t)row * 2048 + h * 128 + n * 16 + l15] = (__bf16)(o[n][i] * inv);
    }
}

// -----------------------------------------------------------------------------
extern "C" void kernel_launch(void* const* d_in, const int* in_sizes, int n_in,
                              void* d_out, int out_size, void* d_ws, size_t ws_size,
                              hipStream_t stream)
{
    const int*   positions = (const int*)d_in[0];
    const float* hidden    = (const float*)d_in[1];
    const float* w_q_a     = (const float*)d_in[2];
    const float* q_a_ln_w  = (const float*)d_in[3];
    const float* w_q_b     = (const float*)d_in[4];
    const float* w_kv_a    = (const float*)d_in[5];
    const float* kv_a_ln_w = (const float*)d_in[6];
    const float* w_kv_b    = (const float*)d_in[7];
    const float* w_o       = (const float*)d_in[8];

    char* ws = (char*)d_ws;
    __bf16* q_a    = (__bf16*)(ws);                    // 2048x1536
    __bf16* q_a_n  = (__bf16*)(ws + 6291456);          // 2048x1536
    __bf16* q      = (__bf16*)(ws + 12582912);         // 2048x3072
    __bf16* latent = (__bf16*)(ws + 25165824);         // 2048x576
    __bf16* kv_a_n = (__bf16*)(ws + 27525120);         // 2048x512
    __bf16* kv     = (__bf16*)(ws + 29622272);         // 2048x4096
    __bf16* qh     = (__bf16*)(ws + 46399488);         // 16x2048x192
    __bf16* kh     = (__bf16*)(ws + 58982400);         // 16x2048x192
    __bf16* vh     = (__bf16*)(ws + 71565312);         // 16x2048x128
    __bf16* attn   = (__bf16*)(ws + 79953920);         // 2048x2048

    dim3 blk(256);
    gemm_any<float, float, __bf16><<<dim3(32, 24), blk, 0, stream>>>(hidden, w_q_a, q_a, 2048, 1536, 2048);
    rmsnorm_k<<<dim3(2048), blk, 0, stream>>>(q_a, 1536, q_a_ln_w, q_a_n, 1536, 1536);
    gemm_any<__bf16, float, __bf16><<<dim3(32, 48), blk, 0, stream>>>(q_a_n, w_q_b, q, 2048, 3072, 1536);
    gemm_any<float, float, __bf16><<<dim3(32, 9), blk, 0, stream>>>(hidden, w_kv_a, latent, 2048, 576, 2048);
    rmsnorm_k<<<dim3(2048), blk, 0, stream>>>(latent, 576, kv_a_ln_w, kv_a_n, 512, 512);
    gemm_any<__bf16, float, __bf16><<<dim3(32, 64), blk, 0, stream>>>(kv_a_n, w_kv_b, kv, 2048, 4096, 512);
    assemble_rope<<<dim3(2048), blk, 0, stream>>>(positions, q, kv, latent, qh, kh, vh);
    attn_flash<<<dim3(32, 16), blk, 0, stream>>>(qh, kh, vh, attn);
    gemm_any<__bf16, float, float><<<dim3(32, 32), blk, 0, stream>>>(attn, w_o, (float*)d_out, 2048, 2048, 2048);
}

// Round 4
// 527.206 us; speedup vs baseline: 1.1996x; 1.1996x over previous
//
#include <hip/hip_runtime.h>
#include <hip/hip_bf16.h>

#define T_ 2048
#define SCALE_ 0.07216878364870322f  // 192^-0.5

typedef __bf16 bf16x8 __attribute__((ext_vector_type(8)));
typedef float f32x4 __attribute__((ext_vector_type(4)));

__device__ inline bf16x8 load8f(const float* p) {
    const float4* f = reinterpret_cast<const float4*>(p);
    float4 a = f[0], b = f[1];
    bf16x8 r;
    r[0] = (__bf16)a.x; r[1] = (__bf16)a.y; r[2] = (__bf16)a.z; r[3] = (__bf16)a.w;
    r[4] = (__bf16)b.x; r[5] = (__bf16)b.y; r[6] = (__bf16)b.z; r[7] = (__bf16)b.w;
    return r;
}

// async global->LDS, 16B per lane; LDS dest must be wave-uniform base (+lane*16 by HW)
__device__ inline void gld_lds16(const void* g, void* l) {
    __builtin_amdgcn_global_load_lds((const __attribute__((address_space(1))) void*)g,
                                     (__attribute__((address_space(3))) void*)l, 16, 0, 0);
}

// ---------------- f32 -> bf16 elementwise ------------------------------------
__global__ __launch_bounds__(256) void cvt_bf16(const float* __restrict__ in,
                                                __bf16* __restrict__ out, int n8)
{
    int i = blockIdx.x * 256 + threadIdx.x;
    if (i < n8)
        *reinterpret_cast<bf16x8*>(out + (size_t)i * 8) = load8f(in + (size_t)i * 8);
}

// ---------------- f32 [K][N] -> bf16 [Npad][K] transpose-convert --------------
// grid: (K/64, Npad/64); N multiple of 64; rows n>=N zero-filled.
__global__ __launch_bounds__(256) void transpose_cvt(
    const float* __restrict__ W, __bf16* __restrict__ Wt, int K, int N)
{
    __shared__ __bf16 tl[64][72];
    const int k0 = blockIdx.x * 64, n0 = blockIdx.y * 64;
    const int tid = threadIdx.x;
    const bool in = n0 < N;
    #pragma unroll
    for (int it = 0; it < 2; ++it) {
        int chunk = tid + it * 256;     // 0..511
        int r = chunk >> 3;             // k row 0..63
        int c8 = (chunk & 7) * 8;       // n col
        float4 a = {0,0,0,0}, b = {0,0,0,0};
        if (in) {
            const float* p = W + (size_t)(k0 + r) * N + n0 + c8;
            a = *reinterpret_cast<const float4*>(p);
            b = *reinterpret_cast<const float4*>(p + 4);
        }
        tl[c8+0][r] = (__bf16)a.x; tl[c8+1][r] = (__bf16)a.y;
        tl[c8+2][r] = (__bf16)a.z; tl[c8+3][r] = (__bf16)a.w;
        tl[c8+4][r] = (__bf16)b.x; tl[c8+5][r] = (__bf16)b.y;
        tl[c8+6][r] = (__bf16)b.z; tl[c8+7][r] = (__bf16)b.w;
    }
    __syncthreads();
    #pragma unroll
    for (int it = 0; it < 2; ++it) {
        int chunk = tid + it * 256;
        int n = chunk >> 3;
        int k8 = (chunk & 7) * 8;
        bf16x8 v = *reinterpret_cast<const bf16x8*>(&tl[n][k8]);
        *reinterpret_cast<bf16x8*>(Wt + (size_t)(n0 + n) * K + k0 + k8) = v;
    }
}

// ---------------- GEMM: C[M,N] = A[M,K] @ Bt[N,K]^T (m97 structure) ----------
// 128x128 tile, BK=32, 4 waves each 64x64 out (4x4 16x16 frags),
// global_load_lds width-16 staging, 2 barriers per K-step.
template <typename TC>
__global__ __launch_bounds__(256) void gemm_bt(
    const __bf16* __restrict__ A, const __bf16* __restrict__ Bt,
    TC* __restrict__ C, int M, int N, int K, int Nstore, int ldc)
{
    __shared__ __bf16 As[128 * 32];
    __shared__ __bf16 Bs[128 * 32];
    const int tid = threadIdx.x, lane = tid & 63, wid = tid >> 6;
    const int l15 = lane & 15, lg = lane >> 4;
    const int m0 = blockIdx.x * 128, n0 = blockIdx.y * 128;
    const int wr = (wid >> 1) * 64, wc = (wid & 1) * 64;

    // staging: wave w covers rows w*32 + j*16 + lane/4, col chunk (lane&3)*8
    const int srow = wid * 32 + (lane >> 2);
    const int scol = (lane & 3) * 8;
    const __bf16* Ag = A  + (size_t)(m0 + srow) * K + scol;
    const __bf16* Bg = Bt + (size_t)(n0 + srow) * K + scol;
    char* ldsA = (char*)As;
    char* ldsB = (char*)Bs;
    const int lbase = wid * 2048;   // bytes

    f32x4 acc[4][4] = {};

    for (int k0 = 0; k0 < K; k0 += 32) {
        __syncthreads();   // previous tile's ds_reads complete
        gld_lds16(Ag + k0,                    ldsA + lbase);
        gld_lds16(Ag + (size_t)16 * K + k0,   ldsA + lbase + 1024);
        gld_lds16(Bg + k0,                    ldsB + lbase);
        gld_lds16(Bg + (size_t)16 * K + k0,   ldsB + lbase + 1024);
        __syncthreads();   // loads landed (vmcnt(0) before barrier)

        bf16x8 af[4], bf[4];
        #pragma unroll
        for (int i = 0; i < 4; ++i) {
            af[i] = *reinterpret_cast<const bf16x8*>(As + (wr + i * 16 + l15) * 32 + lg * 8);
            bf[i] = *reinterpret_cast<const bf16x8*>(Bs + (wc + i * 16 + l15) * 32 + lg * 8);
        }
        #pragma unroll
        for (int i = 0; i < 4; ++i)
            #pragma unroll
            for (int j = 0; j < 4; ++j)
                acc[i][j] = __builtin_amdgcn_mfma_f32_16x16x32_bf16(af[i], bf[j], acc[i][j], 0, 0, 0);
    }

    #pragma unroll
    for (int i = 0; i < 4; ++i)
        #pragma unroll
        for (int j = 0; j < 4; ++j)
            #pragma unroll
            for (int e = 0; e < 4; ++e) {
                int r = m0 + wr + i * 16 + lg * 4 + e;
                int c = n0 + wc + j * 16 + l15;
                if (c < Nstore)
                    C[(size_t)r * ldc + c] = (TC)acc[i][j][e];
            }
}

// ---------------- RMSNorm over rows (bf16 in/out, f32 gamma) ----------------
__global__ __launch_bounds__(256) void rmsnorm_k(
    const __bf16* __restrict__ in, int in_stride,
    const float* __restrict__ w,
    __bf16* __restrict__ out, int out_stride, int W)
{
    const int t = blockIdx.x, tid = threadIdx.x;
    const __bf16* row = in + (size_t)t * in_stride;
    float x[8];
    float ss = 0.f;
    const bool act = tid * 8 < W;
    if (act) {
        bf16x8 v = *reinterpret_cast<const bf16x8*>(row + tid * 8);
        #pragma unroll
        for (int e = 0; e < 8; ++e) { x[e] = (float)v[e]; ss += x[e] * x[e]; }
    }
    #pragma unroll
    for (int m = 1; m < 64; m <<= 1) ss += __shfl_xor(ss, m, 64);
    __shared__ float red[4];
    if ((tid & 63) == 0) red[tid >> 6] = ss;
    __syncthreads();
    float tot = red[0] + red[1] + red[2] + red[3];
    float scale = rsqrtf(tot / (float)W + 1e-6f);
    if (act) {
        float4 w0 = *reinterpret_cast<const float4*>(w + tid * 8);
        float4 w1 = *reinterpret_cast<const float4*>(w + tid * 8 + 4);
        bf16x8 o;
        o[0] = (__bf16)(x[0] * scale * w0.x); o[1] = (__bf16)(x[1] * scale * w0.y);
        o[2] = (__bf16)(x[2] * scale * w0.z); o[3] = (__bf16)(x[3] * scale * w0.w);
        o[4] = (__bf16)(x[4] * scale * w1.x); o[5] = (__bf16)(x[5] * scale * w1.y);
        o[6] = (__bf16)(x[6] * scale * w1.z); o[7] = (__bf16)(x[7] * scale * w1.w);
        *reinterpret_cast<bf16x8*>(out + (size_t)t * out_stride + tid * 8) = o;
    }
}

// ---------------- RoPE: q pe-slices in place + kpe buffer ---------------------
__global__ __launch_bounds__(256) void rope_q_kpe(
    const int* __restrict__ positions, __bf16* __restrict__ q,
    const __bf16* __restrict__ latent, __bf16* __restrict__ kpe)
{
    const int t = blockIdx.x, tid = threadIdx.x;
    __shared__ float cs[32], sn[32];
    if (tid < 32) {
        float pos = (float)positions[t];
        float invf = powf(10000.f, -(float)tid / 32.f);
        float c = cosf(pos * invf), s = sinf(pos * invf);
        cs[tid] = c; sn[tid] = s;
        float x1 = (float)latent[(size_t)t * 576 + 512 + 2 * tid];
        float x2 = (float)latent[(size_t)t * 576 + 513 + 2 * tid];
        kpe[(size_t)t * 64 + 2 * tid]     = (__bf16)(x1 * c - x2 * s);
        kpe[(size_t)t * 64 + 2 * tid + 1] = (__bf16)(x2 * c + x1 * s);
    }
    __syncthreads();
    #pragma unroll
    for (int it = 0; it < 2; ++it) {
        int p = tid + it * 256;          // 0..511 = 16 heads x 32 pairs
        int h = p >> 5, i = p & 31;
        size_t base = (size_t)t * 3072 + h * 192 + 128 + 2 * i;
        float x1 = (float)q[base], x2 = (float)q[base + 1];
        q[base]     = (__bf16)(x1 * cs[i] - x2 * sn[i]);
        q[base + 1] = (__bf16)(x2 * cs[i] + x1 * sn[i]);
    }
}

// ---------------- V transpose: kv[t][h*256+128+d] -> vt[h][d][t] -------------
__global__ __launch_bounds__(256) void vtrans(
    const __bf16* __restrict__ kv, __bf16* __restrict__ vt)
{
    __shared__ __bf16 tile[128][72];
    const int t0 = blockIdx.x * 64;
    const int h  = blockIdx.y;
    const int tid = threadIdx.x;
    #pragma unroll
    for (int it = 0; it < 4; ++it) {
        int chunk = tid + it * 256;      // 0..1023
        int r = chunk >> 4;              // t row 0..63
        int d8 = (chunk & 15) * 8;       // d col
        bf16x8 v = *reinterpret_cast<const bf16x8*>(kv + (size_t)(t0 + r) * 4096 + h * 256 + 128 + d8);
        #pragma unroll
        for (int e = 0; e < 8; ++e) tile[d8 + e][r] = v[e];
    }
    __syncthreads();
    #pragma unroll
    for (int it = 0; it < 4; ++it) {
        int chunk = tid + it * 256;
        int d = chunk >> 3;              // 0..127
        int t8 = (chunk & 7) * 8;
        bf16x8 v = *reinterpret_cast<const bf16x8*>(&tile[d][t8]);
        *reinterpret_cast<bf16x8*>(vt + ((size_t)h * 128 + d) * 2048 + t0 + t8) = v;
    }
}

// ---------------- Flash attention (causal), 1 wave = 16 q rows ---------------
__global__ __launch_bounds__(256) void attn_flash(
    const __bf16* __restrict__ q, const __bf16* __restrict__ kv,
    const __bf16* __restrict__ kpe, const __bf16* __restrict__ vt,
    __bf16* __restrict__ attn)
{
    const int tid = threadIdx.x, lane = tid & 63, wid = tid >> 6;
    const int l15 = lane & 15, lg = lane >> 4;
    const int h  = blockIdx.y;
    const int q0 = blockIdx.x * 64 + wid * 16;

    __shared__ __bf16 plds[4][16][32];

    bf16x8 aq[6];
    #pragma unroll
    for (int c = 0; c < 6; ++c)
        aq[c] = *reinterpret_cast<const bf16x8*>(q + (size_t)(q0 + l15) * 3072 + h * 192 + c * 32 + lg * 8);

    f32x4 o[8] = {};
    float m_i[4], l_i[4];
    #pragma unroll
    for (int i = 0; i < 4; ++i) { m_i[i] = -1e30f; l_i[i] = 0.f; }

    const int smax = q0 + 16;
    for (int s0 = 0; s0 < smax; s0 += 32) {
        f32x4 sa0 = {}, sa1 = {};
        #pragma unroll
        for (int c = 0; c < 4; ++c) {
            bf16x8 k0f = *reinterpret_cast<const bf16x8*>(kv + (size_t)(s0 + l15) * 4096 + h * 256 + c * 32 + lg * 8);
            bf16x8 k1f = *reinterpret_cast<const bf16x8*>(kv + (size_t)(s0 + 16 + l15) * 4096 + h * 256 + c * 32 + lg * 8);
            sa0 = __builtin_amdgcn_mfma_f32_16x16x32_bf16(aq[c], k0f, sa0, 0, 0, 0);
            sa1 = __builtin_amdgcn_mfma_f32_16x16x32_bf16(aq[c], k1f, sa1, 0, 0, 0);
        }
        #pragma unroll
        for (int c = 4; c < 6; ++c) {
            bf16x8 k0f = *reinterpret_cast<const bf16x8*>(kpe + (size_t)(s0 + l15) * 64 + (c - 4) * 32 + lg * 8);
            bf16x8 k1f = *reinterpret_cast<const bf16x8*>(kpe + (size_t)(s0 + 16 + l15) * 64 + (c - 4) * 32 + lg * 8);
            sa0 = __builtin_amdgcn_mfma_f32_16x16x32_bf16(aq[c], k0f, sa0, 0, 0, 0);
            sa1 = __builtin_amdgcn_mfma_f32_16x16x32_bf16(aq[c], k1f, sa1, 0, 0, 0);
        }
        const int col0 = s0 + l15, col1 = s0 + 16 + l15;
        #pragma unroll
        for (int i = 0; i < 4; ++i) {
            const int row = q0 + lg * 4 + i;
            float v0 = sa0[i] * SCALE_; if (col0 > row) v0 = -1e30f;
            float v1 = sa1[i] * SCALE_; if (col1 > row) v1 = -1e30f;
            float mx = fmaxf(v0, v1);
            #pragma unroll
            for (int msk = 1; msk < 16; msk <<= 1) mx = fmaxf(mx, __shfl_xor(mx, msk, 64));
            float mnew = fmaxf(m_i[i], mx);
            float f  = __expf(m_i[i] - mnew);
            float p0 = __expf(v0 - mnew);
            float p1 = __expf(v1 - mnew);
            float ps = p0 + p1;
            #pragma unroll
            for (int msk = 1; msk < 16; msk <<= 1) ps += __shfl_xor(ps, msk, 64);
            l_i[i] = l_i[i] * f + ps;
            m_i[i] = mnew;
            #pragma unroll
            for (int n = 0; n < 8; ++n) o[n][i] *= f;
            plds[wid][lg * 4 + i][l15]      = (__bf16)p0;
            plds[wid][lg * 4 + i][16 + l15] = (__bf16)p1;
        }
        asm volatile("s_waitcnt lgkmcnt(0)" ::: "memory");
        bf16x8 pa = *reinterpret_cast<const bf16x8*>(&plds[wid][l15][lg * 8]);
        #pragma unroll
        for (int n = 0; n < 8; ++n) {
            bf16x8 bv = *reinterpret_cast<const bf16x8*>(vt + ((size_t)h * 128 + n * 16 + l15) * 2048 + s0 + lg * 8);
            o[n] = __builtin_amdgcn_mfma_f32_16x16x32_bf16(pa, bv, o[n], 0, 0, 0);
        }
    }

    #pragma unroll
    for (int i = 0; i < 4; ++i) {
        float inv = 1.f / l_i[i];
        int row = q0 + lg * 4 + i;
        #pragma unroll
        for (int n = 0; n < 8; ++n)
            attn[(size_t)row * 2048 + h * 128 + n * 16 + l15] = (__bf16)(o[n][i] * inv);
    }
}

// -----------------------------------------------------------------------------
extern "C" void kernel_launch(void* const* d_in, const int* in_sizes, int n_in,
                              void* d_out, int out_size, void* d_ws, size_t ws_size,
                              hipStream_t stream)
{
    const int*   positions = (const int*)d_in[0];
    const float* hidden    = (const float*)d_in[1];
    const float* w_q_a     = (const float*)d_in[2];
    const float* q_a_ln_w  = (const float*)d_in[3];
    const float* w_q_b     = (const float*)d_in[4];
    const float* w_kv_a    = (const float*)d_in[5];
    const float* kv_a_ln_w = (const float*)d_in[6];
    const float* w_kv_b    = (const float*)d_in[7];
    const float* w_o       = (const float*)d_in[8];

    char* ws = (char*)d_ws;
    __bf16* hidden_bf = (__bf16*)(ws);                 // 2048x2048      8,388,608
    __bf16* wbuf      = (__bf16*)(ws + 8388608);       // scratch W^T    9,437,184
    __bf16* q_a       = (__bf16*)(ws + 17825792);      // 2048x1536      6,291,456
    __bf16* q_a_n     = (__bf16*)(ws + 24117248);      // 2048x1536      6,291,456
    __bf16* q         = (__bf16*)(ws + 30408704);      // 2048x3072     12,582,912
    __bf16* latent    = (__bf16*)(ws + 42991616);      // 2048x576       2,359,296
    __bf16* kv_a_n    = (__bf16*)(ws + 45350912);      // 2048x512       2,097,152
    __bf16* kv        = (__bf16*)(ws + 47448064);      // 2048x4096     16,777,216
    __bf16* kpe       = (__bf16*)(ws + 64225280);      // 2048x64          262,144
    __bf16* vt        = (__bf16*)(ws + 64487424);      // 16x128x2048    8,388,608
    __bf16* attn      = (__bf16*)(ws + 72876032);      // 2048x2048      8,388,608

    dim3 blk(256);
    cvt_bf16<<<dim3(2048), blk, 0, stream>>>(hidden, hidden_bf, 524288);

    transpose_cvt<<<dim3(32, 24), blk, 0, stream>>>(w_q_a, wbuf, 2048, 1536);
    gemm_bt<__bf16><<<dim3(16, 12), blk, 0, stream>>>(hidden_bf, wbuf, q_a, 2048, 1536, 2048, 1536, 1536);
    rmsnorm_k<<<dim3(2048), blk, 0, stream>>>(q_a, 1536, q_a_ln_w, q_a_n, 1536, 1536);

    transpose_cvt<<<dim3(24, 48), blk, 0, stream>>>(w_q_b, wbuf, 1536, 3072);
    gemm_bt<__bf16><<<dim3(16, 24), blk, 0, stream>>>(q_a_n, wbuf, q, 2048, 3072, 1536, 3072, 3072);

    transpose_cvt<<<dim3(32, 10), blk, 0, stream>>>(w_kv_a, wbuf, 2048, 576);
    gemm_bt<__bf16><<<dim3(16, 5), blk, 0, stream>>>(hidden_bf, wbuf, latent, 2048, 640, 2048, 576, 576);
    rmsnorm_k<<<dim3(2048), blk, 0, stream>>>(latent, 576, kv_a_ln_w, kv_a_n, 512, 512);

    transpose_cvt<<<dim3(8, 64), blk, 0, stream>>>(w_kv_b, wbuf, 512, 4096);
    gemm_bt<__bf16><<<dim3(16, 32), blk, 0, stream>>>(kv_a_n, wbuf, kv, 2048, 4096, 512, 4096, 4096);

    rope_q_kpe<<<dim3(2048), blk, 0, stream>>>(positions, q, latent, kpe);
    vtrans<<<dim3(32, 16), blk, 0, stream>>>(kv, vt);
    attn_flash<<<dim3(32, 16), blk, 0, stream>>>(q, kv, kpe, vt, attn);

    transpose_cvt<<<dim3(32, 32), blk, 0, stream>>>(w_o, wbuf, 2048, 2048);
    gemm_bt<float><<<dim3(16, 16), blk, 0, stream>>>(attn, wbuf, (float*)d_out, 2048, 2048, 2048, 2048, 2048);
}